// Round 2
// baseline (277.588 us; speedup 1.0000x reference)
//
#include <hip/hip_runtime.h>
#include <hip/hip_fp16.h>

#define BB 8
#define NN 1024
#define FF 128
#define HH 8

typedef _Float16 f16;
typedef f16  f16x8 __attribute__((ext_vector_type(8)));
typedef f16  f16x4 __attribute__((ext_vector_type(4)));
typedef float f32x4 __attribute__((ext_vector_type(4)));

#define L2E 1.44269504f

// ---------------- fused preprocessing: conv_x | conv_w | adj bitmask ----------------
// blocks 0..511: x->f16; 512..703: w->wB; 704..2751: adj->bitmask
__global__ void k_pre(const float* __restrict__ x, f16* __restrict__ x16a,
                      const float* __restrict__ w1, const float* __restrict__ w2,
                      const float* __restrict__ w3, f16* __restrict__ wB,
                      const float* __restrict__ adj, unsigned* __restrict__ am){
  int bid = blockIdx.x, t = threadIdx.x;
  if (bid < 512){
    int i = (bid*256 + t)*8;
    float4 a = *(const float4*)(x+i), b = *(const float4*)(x+i+4);
    f16x8 v;
    v[0]=(f16)a.x; v[1]=(f16)a.y; v[2]=(f16)a.z; v[3]=(f16)a.w;
    v[4]=(f16)b.x; v[5]=(f16)b.y; v[6]=(f16)b.z; v[7]=(f16)b.w;
    *(f16x8*)(x16a+i) = v;
  } else if (bid < 704){
    int e = (bid-512)*256 + t;                 // 49152 total
    int fc = e & 15, c = (e>>4)&127, h = (e>>11)&7, l = e>>14;
    const float* w = (l==0) ? w1 : ((l==1) ? w2 : w3);
    f16x8 v;
    #pragma unroll
    for(int j=0;j<8;j++) v[j] = (f16)w[(h*128 + fc*8 + j)*128 + c];
    *(f16x8*)(wB + (((l*8+h)*16 + fc)*128 + c)*8) = v;
  } else {
    int wv = t >> 6, lane = t & 63;
    int r = (bid-704)*4 + wv;                  // 0..8191
    const float* row = adj + (long)r*1024;
    for(int g=0; g<16; g++){
      float v = row[g*64 + lane];
      unsigned long long mb = __ballot(v > 0.0f);
      if (lane == 0){
        am[r*32 + 2*g]   = (unsigned)mb;
        am[r*32 + 2*g+1] = (unsigned)(mb >> 32);
      }
    }
  }
}

// ---------------- hp GEMM: hp = x @ w  (+tanh -> s,d) ----------------
// grid: 512 blocks, 256 threads.  bid decode: h = bid&7 so XCD(bid%8)==h.
// k_attn's block for (b,h) also lands on XCD h (bid%8 = bh%8 = h) -> hpB/sarr/darr
// are written and read on the SAME XCD's L2 (per-XCD L2 is not cross-coherent;
// the old it=bid&7 decode scattered head h's slice across all 8 XCDs).
// hpB layout: [b][h][jc=node/8][c][8]
__global__ __launch_bounds__(256,2) void k_hp(
    const f16* __restrict__ xin,      // [B][N][128] f16
    const f16* __restrict__ wBl,      // [H][16][128][8]
    const float* __restrict__ asrc, const float* __restrict__ adst,  // [H][128]
    f16* __restrict__ hpB,            // [B][H][128][128][8]
    float* __restrict__ sarr, float* __restrict__ darr)              // [B][H][1024]
{
  __shared__ f16 xs[128*136];     // x tile, later reused as tanh tile
  __shared__ float asl[128], adl[128];
  int t = threadIdx.x;
  int bid = blockIdx.x;
  int h = bid & 7, it = (bid>>3)&7, b = bid>>6;   // XCD affinity: bid%8 == h
  int i0 = it*128;
  {
    const f16* src = xin + (long)(b*1024 + i0)*128;
    int fc = t & 15, r0 = t >> 4;
    #pragma unroll
    for(int p=0;p<8;p++){
      int r = r0 + p*16;
      f16x8 v = *(const f16x8*)(src + r*128 + fc*8);
      *(f16x8*)(xs + r*136 + fc*8) = v;
    }
  }
  if (t < 128){ asl[t] = asrc[h*128+t]; adl[t] = adst[h*128+t]; }
  __syncthreads();

  int lane = t & 63, wv = t>>6, wr = wv>>1, wc = wv&1;
  int mq = lane & 15, quad = lane >> 4;
  f32x4 acc[4][4];
  #pragma unroll
  for(int a=0;a<4;a++)
    #pragma unroll
    for(int c=0;c<4;c++) acc[a][c] = (f32x4){0.f,0.f,0.f,0.f};

  const f16* wh = wBl + h*16*128*8;
  #pragma unroll
  for(int ks=0; ks<4; ks++){
    f16x8 af[4], bf[4];
    #pragma unroll
    for(int mt=0; mt<4; mt++)
      af[mt] = *(const f16x8*)(xs + (wr*64 + mt*16 + mq)*136 + ks*32 + quad*8);
    #pragma unroll
    for(int nt=0; nt<4; nt++){
      int c  = wc*64 + nt*16 + mq;
      int fc = ks*4 + quad;
      bf[nt] = *(const f16x8*)(wh + (fc*128 + c)*8);
    }
    #pragma unroll
    for(int mt=0; mt<4; mt++)
      #pragma unroll
      for(int nt=0; nt<4; nt++)
        acc[mt][nt] = __builtin_amdgcn_mfma_f32_16x16x32_f16(af[mt], bf[nt], acc[mt][nt], 0,0,0);
  }
  __syncthreads();          // xs dead -> reuse as tanh tile
  f16* tt = xs;             // [128][136]
  f16* hpb = hpB + (long)(b*8+h)*128*128*8;
  #pragma unroll
  for(int mt=0; mt<4; mt++){
    #pragma unroll
    for(int nt=0; nt<4; nt++){
      int c = wc*64 + nt*16 + mq;
      f16x4 pk;
      #pragma unroll
      for(int rg=0; rg<4; rg++){
        float v = acc[mt][nt][rg];
        pk[rg] = (f16)v;
        int il = wr*64 + mt*16 + quad*4 + rg;    // 0..127
        float e2 = __expf(2.0f*v);
        float th = 1.0f - 2.0f*__builtin_amdgcn_rcpf(e2 + 1.0f);
        tt[il*136 + c] = (f16)th;
      }
      int il0 = wr*64 + mt*16 + quad*4;
      int inode = i0 + il0;
      *(f16x4*)(hpb + ((long)(inode>>3)*128 + c)*8 + (inode&7)) = pk;  // 8B packed store
    }
  }
  __syncthreads();
  {
    int r = t>>1, hf = t&1;
    float s_p = 0.f, d_p = 0.f;
    #pragma unroll
    for(int q=0;q<8;q++){
      f16x8 tv = *(const f16x8*)(tt + r*136 + hf*64 + q*8);
      #pragma unroll
      for(int j=0;j<8;j++){
        float tvf = (float)tv[j];
        int c = hf*64 + q*8 + j;
        s_p = fmaf(tvf, asl[c], s_p);
        d_p = fmaf(tvf, adl[c], d_p);
      }
    }
    s_p += __shfl_xor(s_p, 1);
    d_p += __shfl_xor(d_p, 1);
    if (hf == 0){
      sarr[(b*8+h)*1024 + i0 + r] = s_p;
      darr[(b*8+h)*1024 + i0 + r] = d_p;
    }
  }
}

// ---------------- attention (row-split, dense vectorized P, pipelined) ----------------
// grid: 1024 blocks: bid = it*64 + bh  (same-bh blocks -> XCD bh%8 == h, matching k_hp)
// Each block: 64 rows x all 1024 cols -> z complete in-block; part stored normalized*(1/8).
// Dense P-tile compute (16 cols/thread, f16x8 LDS stores, register bit-mask) replaces
// the divergent while(ctz)-scatter whose dependent scalar LDS reads serialized at
// ~120cy/iteration.  64-col tiles, double-buffered P, B-frags prefetched 1 tile ahead.
__global__ __launch_bounds__(256,4) void k_attn(
    const f16* __restrict__ hpB,      // [B*H][128][128][8]  (jc, c, e)
    const float* __restrict__ sarr, const float* __restrict__ darr,
    const unsigned* __restrict__ am,  // [B*1024][32]
    f16* __restrict__ part)           // [64][1024][128] f16, normalized * 0.125
{
  __shared__ float ddl[1024];         // log2e-scaled d, all columns
  __shared__ float wred[4];
  __shared__ float zl[64];
  __shared__ f16 Pl[2][64*72];        // P tiles, row stride 72 f16 (144B, 16B aligned)
  int t = threadIdx.x;
  int bid = blockIdx.x;
  int bh = bid & 63, it = bid >> 6;
  int i0 = it*64;
  int b = bh >> 3;

  int lane = t&63, wv = t>>6;
  int mq = lane&15, quad = lane>>4;
  const f16* hpb = hpB + (long)bh*128*128*8;

  // stage scaled d (all 1024) + global max of d
  {
    float4 v = *(const float4*)(darr + bh*1024 + t*4);
    float mx = fmaxf(fmaxf(v.x,v.y), fmaxf(v.z,v.w));
    #pragma unroll
    for(int o=1;o<64;o<<=1) mx = fmaxf(mx, __shfl_xor(mx, o));
    if (lane == 0) wred[wv] = mx;
    *(float4*)(ddl + t*4) = make_float4(v.x*L2E, v.y*L2E, v.z*L2E, v.w*L2E);
  }

  int prow = t>>2, pg = t&3;          // row 0..63, 16-col group 0..3
  float srowl = sarr[bh*1024 + i0 + prow] * L2E;
  const unsigned* amrow = am + ((long)(b*1024 + i0 + prow))*32;
  int wsel = pg >> 1, wsh = (pg&1)*16;

  // prefetch B fragments + mask words for tiles 0/1 (no LDS dependency yet)
  f16x8 bcur[4], bnx[4];
  #pragma unroll
  for(int kk=0;kk<2;kk++)
    #pragma unroll
    for(int nt=0;nt<2;nt++){
      int c  = wv*32 + nt*16 + mq;
      int jc = kk*4 + quad;
      bcur[kk*2+nt] = *(const f16x8*)(hpb + ((long)jc*128 + c)*8);
    }
  unsigned wcur = amrow[wsel];
  unsigned wnx  = amrow[2 + wsel];

  __syncthreads();
  float Dml = fmaxf(fmaxf(wred[0],wred[1]), fmaxf(wred[2],wred[3])) * L2E;
  float ml = srowl + Dml;
  float mrowl = fmaxf(ml, 0.2f*ml);   // log2-domain upper bound of masked scores

  f32x4 acc[4][2];
  #pragma unroll
  for(int a=0;a<4;a++){ acc[a][0] = (f32x4){0.f,0.f,0.f,0.f}; acc[a][1] = (f32x4){0.f,0.f,0.f,0.f}; }
  float zacc = 0.f;

  // dense P-tile compute for tile 0 into Pl[0]
  {
    f16* myp = Pl[0] + prow*72 + pg*16;
    unsigned word16 = (wcur >> wsh) & 0xffffu;
    const float* dloc = ddl + pg*16;
    #pragma unroll
    for(int g=0; g<2; g++){
      float4 a0 = *(const float4*)(dloc + g*8);
      float4 a1 = *(const float4*)(dloc + g*8 + 4);
      float vs[8] = {a0.x,a0.y,a0.z,a0.w,a1.x,a1.y,a1.z,a1.w};
      f16x8 pk;
      #pragma unroll
      for(int j=0;j<8;j++){
        float xl  = srowl + vs[j];
        float scl = fmaxf(xl, 0.2f*xl);
        float e   = __builtin_amdgcn_exp2f(scl - mrowl);
        e = ((word16 >> (g*8+j)) & 1u) ? e : 0.f;
        zacc += e;
        pk[j] = (f16)e;
      }
      *(f16x8*)(myp + g*8) = pk;
    }
  }
  __syncthreads();

  for(int jt=0; jt<16; jt++){
    if (jt < 15){
      // prefetch B fragments for tile jt+1
      #pragma unroll
      for(int kk=0;kk<2;kk++)
        #pragma unroll
        for(int nt=0;nt<2;nt++){
          int c  = wv*32 + nt*16 + mq;
          int jc = (jt+1)*8 + kk*4 + quad;
          bnx[kk*2+nt] = *(const f16x8*)(hpb + ((long)jc*128 + c)*8);
        }
      unsigned wfut = (jt < 14) ? amrow[(jt+2)*2 + wsel] : 0u;
      // dense compute of tile jt+1 into the other buffer (disjoint from MFMA reads)
      f16* myp = Pl[(jt+1)&1] + prow*72 + pg*16;
      unsigned word16 = (wnx >> wsh) & 0xffffu;
      const float* dloc = ddl + (jt+1)*64 + pg*16;
      #pragma unroll
      for(int g=0; g<2; g++){
        float4 a0 = *(const float4*)(dloc + g*8);
        float4 a1 = *(const float4*)(dloc + g*8 + 4);
        float vs[8] = {a0.x,a0.y,a0.z,a0.w,a1.x,a1.y,a1.z,a1.w};
        f16x8 pk;
        #pragma unroll
        for(int j=0;j<8;j++){
          float xl  = srowl + vs[j];
          float scl = fmaxf(xl, 0.2f*xl);
          float e   = __builtin_amdgcn_exp2f(scl - mrowl);
          e = ((word16 >> (g*8+j)) & 1u) ? e : 0.f;
          zacc += e;
          pk[j] = (f16)e;
        }
        *(f16x8*)(myp + g*8) = pk;
      }
      wnx = wfut;
    }
    const f16* Pc = Pl[jt&1];
    #pragma unroll
    for(int kk=0;kk<2;kk++){
      #pragma unroll
      for(int mt=0;mt<4;mt++){
        f16x8 a = *(const f16x8*)(Pc + (mt*16+mq)*72 + kk*32 + quad*8);
        #pragma unroll
        for(int nt=0;nt<2;nt++)
          acc[mt][nt] = __builtin_amdgcn_mfma_f32_16x16x32_f16(a, bcur[kk*2+nt], acc[mt][nt], 0,0,0);
      }
    }
    __syncthreads();
    if (jt < 15){
      #pragma unroll
      for(int q=0;q<4;q++) bcur[q] = bnx[q];
    }
  }

  // full softmax denominator per row (4-lane group covers all 1024 cols)
  zacc += __shfl_xor(zacc, 1);
  zacc += __shfl_xor(zacc, 2);
  if (pg == 0) zl[prow] = zacc;
  __syncthreads();

  // normalize + head-prescale, transpose through LDS for coalesced f16x8 stores
  f16* Ps = (f16*)Pl;                  // [64][136] f16 (272B stride, 16B aligned)
  #pragma unroll
  for(int mt=0;mt<4;mt++){
    #pragma unroll
    for(int rg=0;rg<4;rg++){
      int il = mt*16 + quad*4 + rg;
      float zi = 0.125f * __builtin_amdgcn_rcpf(zl[il]);
      #pragma unroll
      for(int nt=0;nt<2;nt++){
        int c = wv*32 + nt*16 + mq;
        Ps[il*136 + c] = (f16)(acc[mt][nt][rg] * zi);
      }
    }
  }
  __syncthreads();
  {
    int r = t>>2, g = t&3;
    f16* dst = part + ((long)bh*1024 + i0 + r)*128 + g*32;
    const f16* srcp = Ps + r*136 + g*32;
    *(f16x8*)(dst)    = *(const f16x8*)(srcp);
    *(f16x8*)(dst+8)  = *(const f16x8*)(srcp+8);
    *(f16x8*)(dst+16) = *(const f16x8*)(srcp+16);
    *(f16x8*)(dst+24) = *(const f16x8*)(srcp+24);
  }
}

// ---------------- finalize: sum heads (already normalized+prescaled), bias(+relu), partial node-max ----------------
// 512 blocks x 256: block covers one b, 16 nodes, all 128 channels
__global__ void k_fin(const f16* __restrict__ part, const float* __restrict__ bias,
                      f16* __restrict__ x16, float* __restrict__ pmax, int do_relu){
  __shared__ float pm[16][128];
  int t = threadIdx.x;
  int idx = blockIdx.x*256 + t;   // b(3)|n(10)|c8(4)
  int c8 = idx & 15, n = (idx>>4)&1023, b = idx>>14;
  float s[8];
  #pragma unroll
  for(int j=0;j<8;j++) s[j] = 0.f;
  #pragma unroll
  for(int h=0;h<8;h++){
    int bh = b*8 + h;
    f16x8 p0 = *(const f16x8*)(part + ((long)bh*1024 + n)*128 + c8*8);
    #pragma unroll
    for(int j=0;j<8;j++) s[j] += (float)p0[j];
  }
  f16x8 h8;
  float ov[8];
  #pragma unroll
  for(int j=0;j<8;j++){
    float v = s[j] + bias[c8*8 + j];
    if (do_relu) v = fmaxf(v, 0.f);
    ov[j] = v;
    h8[j] = (f16)v;
  }
  if (x16) *(f16x8*)(x16 + ((long)(b*1024+n))*128 + c8*8) = h8;
  #pragma unroll
  for(int j=0;j<8;j++) pm[n&15][c8*8+j] = ov[j];
  __syncthreads();
  if (t < 128){
    float m = pm[0][t];
    #pragma unroll
    for(int r=1;r<16;r++) m = fmaxf(m, pm[r][t]);
    pmax[blockIdx.x*128 + t] = m;   // [b*64+chunk][128]
  }
}

// ---------------- final: max over chunks + predictor ----------------
__global__ void k_pool2(const float* __restrict__ pmax, const float* __restrict__ pw,
                        const float* __restrict__ pb, float* __restrict__ out){
  __shared__ float pl[384];
  int b = blockIdx.x, t = threadIdx.x;
  for(int f = t; f < 384; f += 256){
    int l = f >> 7, c = f & 127;
    const float* p = pmax + l*65536 + b*64*128 + c;
    float mx = -3.4e38f;
    #pragma unroll 8
    for(int k=0;k<64;k++) mx = fmaxf(mx, p[k*128]);
    pl[f] = mx;
  }
  __syncthreads();
  if (t < 64){
    float a0 = 0.f, a1 = 0.f;
    #pragma unroll
    for(int k=0;k<6;k++){
      int f = t + 64*k;
      float v = pl[f];
      a0 = fmaf(v, pw[f*2],   a0);
      a1 = fmaf(v, pw[f*2+1], a1);
    }
    #pragma unroll
    for(int o=1;o<64;o<<=1){ a0 += __shfl_xor(a0,o); a1 += __shfl_xor(a1,o); }
    if (t == 0){ out[b*2] = a0 + pb[0]; out[b*2+1] = a1 + pb[1]; }
  }
}

// ---------------- launcher ----------------
extern "C" void kernel_launch(void* const* d_in, const int* in_sizes, int n_in,
                              void* d_out, int out_size, void* d_ws, size_t ws_size,
                              hipStream_t stream) {
  const float* x   = (const float*)d_in[0];
  const float* adj = (const float*)d_in[1];
  const float* w1  = (const float*)d_in[2];
  const float* as1 = (const float*)d_in[3];
  const float* ad1 = (const float*)d_in[4];
  const float* b1  = (const float*)d_in[5];
  const float* w2  = (const float*)d_in[6];
  const float* as2 = (const float*)d_in[7];
  const float* ad2 = (const float*)d_in[8];
  const float* b2  = (const float*)d_in[9];
  const float* w3  = (const float*)d_in[10];
  const float* as3 = (const float*)d_in[11];
  const float* ad3 = (const float*)d_in[12];
  const float* b3  = (const float*)d_in[13];
  const float* pw  = (const float*)d_in[14];
  const float* pb  = (const float*)d_in[15];

  char* ws = (char*)d_ws;
  f16*      x16a = (f16*)ws;                 ws += (size_t)1048576*2;
  f16*      x16b = (f16*)ws;                 ws += (size_t)1048576*2;
  f16*      wB   = (f16*)ws;                 ws += (size_t)393216*2;
  unsigned* am   = (unsigned*)ws;            ws += (size_t)8*1024*32*4;
  f16*      hpB  = (f16*)ws;                 ws += (size_t)8*8*1024*128*2;
  float*    sarr = (float*)ws;               ws += (size_t)65536*4;
  float*    darr = (float*)ws;               ws += (size_t)65536*4;
  f16*      part = (f16*)ws;                 ws += (size_t)64*1024*128*2;
  float*    pmax = (float*)ws;               ws += (size_t)3*512*128*4;

  k_pre<<<2752, 256, 0, stream>>>(x, x16a, w1, w2, w3, wB, adj, am);

  // layer 1
  k_hp  <<<512, 256, 0, stream>>>(x16a, wB,            as1, ad1, hpB, sarr, darr);
  k_attn<<<1024,256, 0, stream>>>(hpB, sarr, darr, am, part);
  k_fin <<<512, 256, 0, stream>>>(part, b1, x16b, pmax,           1);
  // layer 2
  k_hp  <<<512, 256, 0, stream>>>(x16b, wB + 131072,   as2, ad2, hpB, sarr, darr);
  k_attn<<<1024,256, 0, stream>>>(hpB, sarr, darr, am, part);
  k_fin <<<512, 256, 0, stream>>>(part, b2, x16a, pmax + 65536,   1);
  // layer 3
  k_hp  <<<512, 256, 0, stream>>>(x16a, wB + 262144,   as3, ad3, hpB, sarr, darr);
  k_attn<<<1024,256, 0, stream>>>(hpB, sarr, darr, am, part);
  k_fin <<<512, 256, 0, stream>>>(part, b3, nullptr, pmax + 131072, 0);

  k_pool2<<<8, 256, 0, stream>>>(pmax, pw, pb, (float*)d_out);
}

// Round 3
// 263.324 us; speedup vs baseline: 1.0542x; 1.0542x over previous
//
#include <hip/hip_runtime.h>
#include <hip/hip_fp16.h>

#define BB 8
#define NN 1024
#define FF 128
#define HH 8

typedef _Float16 f16;
typedef f16  f16x8 __attribute__((ext_vector_type(8)));
typedef f16  f16x4 __attribute__((ext_vector_type(4)));
typedef float f32x4 __attribute__((ext_vector_type(4)));

#define L2E 1.44269504f

// ---------------- fused preprocessing: conv_x | conv_w | adj bitmask ----------------
// blocks 0..511: x->f16; 512..703: w->wB; 704..2751: adj->bitmask
__global__ void k_pre(const float* __restrict__ x, f16* __restrict__ x16a,
                      const float* __restrict__ w1, const float* __restrict__ w2,
                      const float* __restrict__ w3, f16* __restrict__ wB,
                      const float* __restrict__ adj, unsigned* __restrict__ am){
  int bid = blockIdx.x, t = threadIdx.x;
  if (bid < 512){
    int i = (bid*256 + t)*8;
    float4 a = *(const float4*)(x+i), b = *(const float4*)(x+i+4);
    f16x8 v;
    v[0]=(f16)a.x; v[1]=(f16)a.y; v[2]=(f16)a.z; v[3]=(f16)a.w;
    v[4]=(f16)b.x; v[5]=(f16)b.y; v[6]=(f16)b.z; v[7]=(f16)b.w;
    *(f16x8*)(x16a+i) = v;
  } else if (bid < 704){
    int e = (bid-512)*256 + t;                 // 49152 total
    int fc = e & 15, c = (e>>4)&127, h = (e>>11)&7, l = e>>14;
    const float* w = (l==0) ? w1 : ((l==1) ? w2 : w3);
    f16x8 v;
    #pragma unroll
    for(int j=0;j<8;j++) v[j] = (f16)w[(h*128 + fc*8 + j)*128 + c];
    *(f16x8*)(wB + (((l*8+h)*16 + fc)*128 + c)*8) = v;
  } else {
    int wv = t >> 6, lane = t & 63;
    int r = (bid-704)*4 + wv;                  // 0..8191
    const float* row = adj + (long)r*1024;
    for(int g=0; g<16; g++){
      float v = row[g*64 + lane];
      unsigned long long mb = __ballot(v > 0.0f);
      if (lane == 0){
        am[r*32 + 2*g]   = (unsigned)mb;
        am[r*32 + 2*g+1] = (unsigned)(mb >> 32);
      }
    }
  }
}

// ---------------- hp GEMM: hp = x @ w  (+tanh -> s,d) ----------------
// grid: 512 blocks, 256 threads.  bid decode: h = bid&7 so XCD(bid%8)==h.
// k_attn's block for (b,h) also lands on XCD h (bid%8 = bh%8 = h) -> hpB/sarr/darr
// are written and read on the SAME XCD's L2 (per-XCD L2 is not cross-coherent;
// an it=bid&7 decode scatters head h's slice across all 8 XCDs).
// hpB layout: [b][h][jc=node/8][c][8]
__global__ __launch_bounds__(256,2) void k_hp(
    const f16* __restrict__ xin,      // [B][N][128] f16
    const f16* __restrict__ wBl,      // [H][16][128][8]
    const float* __restrict__ asrc, const float* __restrict__ adst,  // [H][128]
    f16* __restrict__ hpB,            // [B][H][128][128][8]
    float* __restrict__ sarr, float* __restrict__ darr)              // [B][H][1024]
{
  __shared__ f16 xs[128*136];     // x tile, later reused as tanh tile
  __shared__ float asl[128], adl[128];
  int t = threadIdx.x;
  int bid = blockIdx.x;
  int h = bid & 7, it = (bid>>3)&7, b = bid>>6;   // XCD affinity: bid%8 == h
  int i0 = it*128;
  {
    const f16* src = xin + (long)(b*1024 + i0)*128;
    int fc = t & 15, r0 = t >> 4;
    #pragma unroll
    for(int p=0;p<8;p++){
      int r = r0 + p*16;
      f16x8 v = *(const f16x8*)(src + r*128 + fc*8);
      *(f16x8*)(xs + r*136 + fc*8) = v;
    }
  }
  if (t < 128){ asl[t] = asrc[h*128+t]; adl[t] = adst[h*128+t]; }
  __syncthreads();

  int lane = t & 63, wv = t>>6, wr = wv>>1, wc = wv&1;
  int mq = lane & 15, quad = lane >> 4;
  f32x4 acc[4][4];
  #pragma unroll
  for(int a=0;a<4;a++)
    #pragma unroll
    for(int c=0;c<4;c++) acc[a][c] = (f32x4){0.f,0.f,0.f,0.f};

  const f16* wh = wBl + h*16*128*8;
  #pragma unroll
  for(int ks=0; ks<4; ks++){
    f16x8 af[4], bf[4];
    #pragma unroll
    for(int mt=0; mt<4; mt++)
      af[mt] = *(const f16x8*)(xs + (wr*64 + mt*16 + mq)*136 + ks*32 + quad*8);
    #pragma unroll
    for(int nt=0; nt<4; nt++){
      int c  = wc*64 + nt*16 + mq;
      int fc = ks*4 + quad;
      bf[nt] = *(const f16x8*)(wh + (fc*128 + c)*8);
    }
    #pragma unroll
    for(int mt=0; mt<4; mt++)
      #pragma unroll
      for(int nt=0; nt<4; nt++)
        acc[mt][nt] = __builtin_amdgcn_mfma_f32_16x16x32_f16(af[mt], bf[nt], acc[mt][nt], 0,0,0);
  }
  __syncthreads();          // xs dead -> reuse as tanh tile
  f16* tt = xs;             // [128][136]
  f16* hpb = hpB + (long)(b*8+h)*128*128*8;
  #pragma unroll
  for(int mt=0; mt<4; mt++){
    #pragma unroll
    for(int nt=0; nt<4; nt++){
      int c = wc*64 + nt*16 + mq;
      f16x4 pk;
      #pragma unroll
      for(int rg=0; rg<4; rg++){
        float v = acc[mt][nt][rg];
        pk[rg] = (f16)v;
        int il = wr*64 + mt*16 + quad*4 + rg;    // 0..127
        float e2 = __expf(2.0f*v);
        float th = 1.0f - 2.0f*__builtin_amdgcn_rcpf(e2 + 1.0f);
        tt[il*136 + c] = (f16)th;
      }
      int il0 = wr*64 + mt*16 + quad*4;
      int inode = i0 + il0;
      *(f16x4*)(hpb + ((long)(inode>>3)*128 + c)*8 + (inode&7)) = pk;  // 8B packed store
    }
  }
  __syncthreads();
  {
    int r = t>>1, hf = t&1;
    float s_p = 0.f, d_p = 0.f;
    #pragma unroll
    for(int q=0;q<8;q++){
      f16x8 tv = *(const f16x8*)(tt + r*136 + hf*64 + q*8);
      #pragma unroll
      for(int j=0;j<8;j++){
        float tvf = (float)tv[j];
        int c = hf*64 + q*8 + j;
        s_p = fmaf(tvf, asl[c], s_p);
        d_p = fmaf(tvf, adl[c], d_p);
      }
    }
    s_p += __shfl_xor(s_p, 1);
    d_p += __shfl_xor(d_p, 1);
    if (hf == 0){
      sarr[(b*8+h)*1024 + i0 + r] = s_p;
      darr[(b*8+h)*1024 + i0 + r] = d_p;
    }
  }
}

// ---------------- attention (row-split, full-j per block, pipelined) ----------------
// grid: 1024 blocks: bid = it*64 + bh  (same-bh blocks -> XCD bh%8 == h, matching k_hp)
// Each block: 64 rows x all 1024 cols -> z complete in-block; part stored normalized*(1/8).
// Sparse ctz-scatter P-fill (~3.3 exps per 64-col row at 5% density; dense 16-exp/thread
// variant cost +18us of TRANS/VALU issue in R2).  64-col tiles, double-buffered P,
// B-frags + mask words prefetched one tile ahead so global-load latency hides under MFMA.
__global__ __launch_bounds__(256,4) void k_attn(
    const f16* __restrict__ hpB,      // [B*H][128][128][8]  (jc, c, e)
    const float* __restrict__ sarr, const float* __restrict__ darr,
    const unsigned* __restrict__ am,  // [B*1024][32]
    f16* __restrict__ part)           // [64][1024][128] f16, normalized * 0.125
{
  __shared__ float ddl[1024];         // log2e-scaled d, all columns
  __shared__ float wred[4];
  __shared__ float zl[64];
  __shared__ f16 Pl[2][64*72];        // P tiles, row stride 72 f16 (144B, 16B aligned)
  int t = threadIdx.x;
  int bid = blockIdx.x;
  int bh = bid & 63, it = bid >> 6;
  int i0 = it*64;
  int b = bh >> 3;

  int lane = t&63, wv = t>>6;
  int mq = lane&15, quad = lane>>4;
  const f16* hpb = hpB + (long)bh*128*128*8;

  // stage scaled d (all 1024) + global max of d
  {
    float4 v = *(const float4*)(darr + bh*1024 + t*4);
    float mx = fmaxf(fmaxf(v.x,v.y), fmaxf(v.z,v.w));
    #pragma unroll
    for(int o=1;o<64;o<<=1) mx = fmaxf(mx, __shfl_xor(mx, o));
    if (lane == 0) wred[wv] = mx;
    *(float4*)(ddl + t*4) = make_float4(v.x*L2E, v.y*L2E, v.z*L2E, v.w*L2E);
  }

  int prow = t>>2, pg = t&3;          // row 0..63, 16-col group 0..3
  float srowl = sarr[bh*1024 + i0 + prow] * L2E;
  const unsigned* amrow = am + ((long)(b*1024 + i0 + prow))*32;
  int wsel = pg >> 1, wsh = (pg&1)*16;

  // prefetch B fragments + mask words for tiles 0/1 (no LDS dependency yet)
  f16x8 bcur[4], bnx[4];
  #pragma unroll
  for(int kk=0;kk<2;kk++)
    #pragma unroll
    for(int nt=0;nt<2;nt++){
      int c  = wv*32 + nt*16 + mq;
      int jc = kk*4 + quad;
      bcur[kk*2+nt] = *(const f16x8*)(hpb + ((long)jc*128 + c)*8);
    }
  unsigned wcur = amrow[wsel];
  unsigned wnx  = amrow[2 + wsel];

  __syncthreads();
  float Dml = fmaxf(fmaxf(wred[0],wred[1]), fmaxf(wred[2],wred[3])) * L2E;
  float ml = srowl + Dml;
  float mrowl = fmaxf(ml, 0.2f*ml);   // log2-domain upper bound of masked scores

  f32x4 acc[4][2];
  #pragma unroll
  for(int a=0;a<4;a++){ acc[a][0] = (f32x4){0.f,0.f,0.f,0.f}; acc[a][1] = (f32x4){0.f,0.f,0.f,0.f}; }
  float zacc = 0.f;
  f16x8 zerov = (f16x8){0,0,0,0,0,0,0,0};

  // scatter tile 0 into Pl[0]
  {
    f16* myp = Pl[0] + prow*72 + pg*16;
    *(f16x8*)myp = zerov; *(f16x8*)(myp+8) = zerov;
    unsigned word = (wcur >> wsh) & 0xffffu;
    const float* dloc = ddl + pg*16;
    while(word){
      int j = __builtin_ctz(word); word &= word - 1u;
      float xl  = srowl + dloc[j];
      float scl = fmaxf(xl, 0.2f*xl);
      float e   = __builtin_amdgcn_exp2f(scl - mrowl);
      zacc += e;
      myp[j] = (f16)e;
    }
  }
  __syncthreads();

  for(int jt=0; jt<16; jt++){
    if (jt < 15){
      // prefetch B fragments for tile jt+1
      #pragma unroll
      for(int kk=0;kk<2;kk++)
        #pragma unroll
        for(int nt=0;nt<2;nt++){
          int c  = wv*32 + nt*16 + mq;
          int jc = (jt+1)*8 + kk*4 + quad;
          bnx[kk*2+nt] = *(const f16x8*)(hpb + ((long)jc*128 + c)*8);
        }
      unsigned wfut = (jt < 14) ? amrow[(jt+2)*2 + wsel] : 0u;
      // scatter tile jt+1 into the other buffer (disjoint from MFMA reads of tile jt)
      f16* myp = Pl[(jt+1)&1] + prow*72 + pg*16;
      *(f16x8*)myp = zerov; *(f16x8*)(myp+8) = zerov;
      unsigned word = (wnx >> wsh) & 0xffffu;
      const float* dloc = ddl + (jt+1)*64 + pg*16;
      while(word){
        int j = __builtin_ctz(word); word &= word - 1u;
        float xl  = srowl + dloc[j];
        float scl = fmaxf(xl, 0.2f*xl);
        float e   = __builtin_amdgcn_exp2f(scl - mrowl);
        zacc += e;
        myp[j] = (f16)e;
      }
      wnx = wfut;
    }
    const f16* Pc = Pl[jt&1];
    #pragma unroll
    for(int kk=0;kk<2;kk++){
      #pragma unroll
      for(int mt=0;mt<4;mt++){
        f16x8 a = *(const f16x8*)(Pc + (mt*16+mq)*72 + kk*32 + quad*8);
        #pragma unroll
        for(int nt=0;nt<2;nt++)
          acc[mt][nt] = __builtin_amdgcn_mfma_f32_16x16x32_f16(a, bcur[kk*2+nt], acc[mt][nt], 0,0,0);
      }
    }
    __syncthreads();
    if (jt < 15){
      #pragma unroll
      for(int q=0;q<4;q++) bcur[q] = bnx[q];
    }
  }

  // full softmax denominator per row (4-lane group covers all 1024 cols)
  zacc += __shfl_xor(zacc, 1);
  zacc += __shfl_xor(zacc, 2);
  if (pg == 0) zl[prow] = zacc;
  __syncthreads();

  // normalize + head-prescale, transpose through LDS for coalesced f16x8 stores
  f16* Ps = (f16*)Pl;                  // [64][136] f16 (272B stride, 16B aligned)
  #pragma unroll
  for(int mt=0;mt<4;mt++){
    #pragma unroll
    for(int rg=0;rg<4;rg++){
      int il = mt*16 + quad*4 + rg;
      float zi = 0.125f * __builtin_amdgcn_rcpf(zl[il]);
      #pragma unroll
      for(int nt=0;nt<2;nt++){
        int c = wv*32 + nt*16 + mq;
        Ps[il*136 + c] = (f16)(acc[mt][nt][rg] * zi);
      }
    }
  }
  __syncthreads();
  {
    int r = t>>2, g = t&3;
    f16* dst = part + ((long)bh*1024 + i0 + r)*128 + g*32;
    const f16* srcp = Ps + r*136 + g*32;
    *(f16x8*)(dst)    = *(const f16x8*)(srcp);
    *(f16x8*)(dst+8)  = *(const f16x8*)(srcp+8);
    *(f16x8*)(dst+16) = *(const f16x8*)(srcp+16);
    *(f16x8*)(dst+24) = *(const f16x8*)(srcp+24);
  }
}

// ---------------- finalize: sum heads (already normalized+prescaled), bias(+relu), partial node-max ----------------
// 512 blocks x 256: block covers one b, 16 nodes, all 128 channels
__global__ void k_fin(const f16* __restrict__ part, const float* __restrict__ bias,
                      f16* __restrict__ x16, float* __restrict__ pmax, int do_relu){
  __shared__ float pm[16][128];
  int t = threadIdx.x;
  int idx = blockIdx.x*256 + t;   // b(3)|n(10)|c8(4)
  int c8 = idx & 15, n = (idx>>4)&1023, b = idx>>14;
  float s[8];
  #pragma unroll
  for(int j=0;j<8;j++) s[j] = 0.f;
  #pragma unroll
  for(int h=0;h<8;h++){
    int bh = b*8 + h;
    f16x8 p0 = *(const f16x8*)(part + ((long)bh*1024 + n)*128 + c8*8);
    #pragma unroll
    for(int j=0;j<8;j++) s[j] += (float)p0[j];
  }
  f16x8 h8;
  float ov[8];
  #pragma unroll
  for(int j=0;j<8;j++){
    float v = s[j] + bias[c8*8 + j];
    if (do_relu) v = fmaxf(v, 0.f);
    ov[j] = v;
    h8[j] = (f16)v;
  }
  if (x16) *(f16x8*)(x16 + ((long)(b*1024+n))*128 + c8*8) = h8;
  #pragma unroll
  for(int j=0;j<8;j++) pm[n&15][c8*8+j] = ov[j];
  __syncthreads();
  if (t < 128){
    float m = pm[0][t];
    #pragma unroll
    for(int r=1;r<16;r++) m = fmaxf(m, pm[r][t]);
    pmax[blockIdx.x*128 + t] = m;   // [b*64+chunk][128]
  }
}

// ---------------- final: max over chunks + predictor ----------------
__global__ void k_pool2(const float* __restrict__ pmax, const float* __restrict__ pw,
                        const float* __restrict__ pb, float* __restrict__ out){
  __shared__ float pl[384];
  int b = blockIdx.x, t = threadIdx.x;
  for(int f = t; f < 384; f += 256){
    int l = f >> 7, c = f & 127;
    const float* p = pmax + l*65536 + b*64*128 + c;
    float mx = -3.4e38f;
    #pragma unroll 8
    for(int k=0;k<64;k++) mx = fmaxf(mx, p[k*128]);
    pl[f] = mx;
  }
  __syncthreads();
  if (t < 64){
    float a0 = 0.f, a1 = 0.f;
    #pragma unroll
    for(int k=0;k<6;k++){
      int f = t + 64*k;
      float v = pl[f];
      a0 = fmaf(v, pw[f*2],   a0);
      a1 = fmaf(v, pw[f*2+1], a1);
    }
    #pragma unroll
    for(int o=1;o<64;o<<=1){ a0 += __shfl_xor(a0,o); a1 += __shfl_xor(a1,o); }
    if (t == 0){ out[b*2] = a0 + pb[0]; out[b*2+1] = a1 + pb[1]; }
  }
}

// ---------------- launcher ----------------
extern "C" void kernel_launch(void* const* d_in, const int* in_sizes, int n_in,
                              void* d_out, int out_size, void* d_ws, size_t ws_size,
                              hipStream_t stream) {
  const float* x   = (const float*)d_in[0];
  const float* adj = (const float*)d_in[1];
  const float* w1  = (const float*)d_in[2];
  const float* as1 = (const float*)d_in[3];
  const float* ad1 = (const float*)d_in[4];
  const float* b1  = (const float*)d_in[5];
  const float* w2  = (const float*)d_in[6];
  const float* as2 = (const float*)d_in[7];
  const float* ad2 = (const float*)d_in[8];
  const float* b2  = (const float*)d_in[9];
  const float* w3  = (const float*)d_in[10];
  const float* as3 = (const float*)d_in[11];
  const float* ad3 = (const float*)d_in[12];
  const float* b3  = (const float*)d_in[13];
  const float* pw  = (const float*)d_in[14];
  const float* pb  = (const float*)d_in[15];

  char* ws = (char*)d_ws;
  f16*      x16a = (f16*)ws;                 ws += (size_t)1048576*2;
  f16*      x16b = (f16*)ws;                 ws += (size_t)1048576*2;
  f16*      wB   = (f16*)ws;                 ws += (size_t)393216*2;
  unsigned* am   = (unsigned*)ws;            ws += (size_t)8*1024*32*4;
  f16*      hpB  = (f16*)ws;                 ws += (size_t)8*8*1024*128*2;
  float*    sarr = (float*)ws;               ws += (size_t)65536*4;
  float*    darr = (float*)ws;               ws += (size_t)65536*4;
  f16*      part = (f16*)ws;                 ws += (size_t)64*1024*128*2;
  float*    pmax = (float*)ws;               ws += (size_t)3*512*128*4;

  k_pre<<<2752, 256, 0, stream>>>(x, x16a, w1, w2, w3, wB, adj, am);

  // layer 1
  k_hp  <<<512, 256, 0, stream>>>(x16a, wB,            as1, ad1, hpB, sarr, darr);
  k_attn<<<1024,256, 0, stream>>>(hpB, sarr, darr, am, part);
  k_fin <<<512, 256, 0, stream>>>(part, b1, x16b, pmax,           1);
  // layer 2
  k_hp  <<<512, 256, 0, stream>>>(x16b, wB + 131072,   as2, ad2, hpB, sarr, darr);
  k_attn<<<1024,256, 0, stream>>>(hpB, sarr, darr, am, part);
  k_fin <<<512, 256, 0, stream>>>(part, b2, x16a, pmax + 65536,   1);
  // layer 3
  k_hp  <<<512, 256, 0, stream>>>(x16a, wB + 262144,   as3, ad3, hpB, sarr, darr);
  k_attn<<<1024,256, 0, stream>>>(hpB, sarr, darr, am, part);
  k_fin <<<512, 256, 0, stream>>>(part, b3, nullptr, pmax + 131072, 0);

  k_pool2<<<8, 256, 0, stream>>>(pmax, pw, pb, (float*)d_out);
}

// Round 4
// 254.850 us; speedup vs baseline: 1.0892x; 1.0333x over previous
//
#include <hip/hip_runtime.h>
#include <hip/hip_fp16.h>

#define BB 8
#define NN 1024
#define FF 128
#define HH 8

typedef _Float16 f16;
typedef f16  f16x8 __attribute__((ext_vector_type(8)));
typedef f16  f16x4 __attribute__((ext_vector_type(4)));
typedef float f32x4 __attribute__((ext_vector_type(4)));

#define L2E 1.44269504f

// ---------------- fused preprocessing: conv_x | conv_w | adj bitmask ----------------
// blocks 0..511: x->f16; 512..703: w->wB; 704..2751: adj->bitmask
__global__ void k_pre(const float* __restrict__ x, f16* __restrict__ x16a,
                      const float* __restrict__ w1, const float* __restrict__ w2,
                      const float* __restrict__ w3, f16* __restrict__ wB,
                      const float* __restrict__ adj, unsigned* __restrict__ am){
  int bid = blockIdx.x, t = threadIdx.x;
  if (bid < 512){
    int i = (bid*256 + t)*8;
    float4 a = *(const float4*)(x+i), b = *(const float4*)(x+i+4);
    f16x8 v;
    v[0]=(f16)a.x; v[1]=(f16)a.y; v[2]=(f16)a.z; v[3]=(f16)a.w;
    v[4]=(f16)b.x; v[5]=(f16)b.y; v[6]=(f16)b.z; v[7]=(f16)b.w;
    *(f16x8*)(x16a+i) = v;
  } else if (bid < 704){
    int e = (bid-512)*256 + t;                 // 49152 total
    int fc = e & 15, c = (e>>4)&127, h = (e>>11)&7, l = e>>14;
    const float* w = (l==0) ? w1 : ((l==1) ? w2 : w3);
    f16x8 v;
    #pragma unroll
    for(int j=0;j<8;j++) v[j] = (f16)w[(h*128 + fc*8 + j)*128 + c];
    *(f16x8*)(wB + (((l*8+h)*16 + fc)*128 + c)*8) = v;
  } else {
    int wv = t >> 6, lane = t & 63;
    int r = (bid-704)*4 + wv;                  // 0..8191
    const float* row = adj + (long)r*1024;
    for(int g=0; g<16; g++){
      float v = row[g*64 + lane];
      unsigned long long mb = __ballot(v > 0.0f);
      if (lane == 0){
        am[r*32 + 2*g]   = (unsigned)mb;
        am[r*32 + 2*g+1] = (unsigned)(mb >> 32);
      }
    }
  }
}

// ---------------- hp GEMM: hp = x @ w  (+tanh -> s,d) ----------------
// grid: 512 blocks, 256 threads.  bid decode: h = bid&7 so XCD(bid%8)==h  (neutral in
// R3 A/B, kept: mechanism sound, no measured harm).
// hpB layout: [b][h][jc=node/8][c][8]
__global__ __launch_bounds__(256,2) void k_hp(
    const f16* __restrict__ xin,      // [B][N][128] f16
    const f16* __restrict__ wBl,      // [H][16][128][8]
    const float* __restrict__ asrc, const float* __restrict__ adst,  // [H][128]
    f16* __restrict__ hpB,            // [B][H][128][128][8]
    float* __restrict__ sarr, float* __restrict__ darr)              // [B][H][1024]
{
  __shared__ f16 xs[128*136];     // x tile, later reused as tanh tile
  __shared__ float asl[128], adl[128];
  int t = threadIdx.x;
  int bid = blockIdx.x;
  int h = bid & 7, it = (bid>>3)&7, b = bid>>6;   // XCD affinity: bid%8 == h
  int i0 = it*128;
  {
    const f16* src = xin + (long)(b*1024 + i0)*128;
    int fc = t & 15, r0 = t >> 4;
    #pragma unroll
    for(int p=0;p<8;p++){
      int r = r0 + p*16;
      f16x8 v = *(const f16x8*)(src + r*128 + fc*8);
      *(f16x8*)(xs + r*136 + fc*8) = v;
    }
  }
  if (t < 128){ asl[t] = asrc[h*128+t]; adl[t] = adst[h*128+t]; }
  __syncthreads();

  int lane = t & 63, wv = t>>6, wr = wv>>1, wc = wv&1;
  int mq = lane & 15, quad = lane >> 4;
  f32x4 acc[4][4];
  #pragma unroll
  for(int a=0;a<4;a++)
    #pragma unroll
    for(int c=0;c<4;c++) acc[a][c] = (f32x4){0.f,0.f,0.f,0.f};

  const f16* wh = wBl + h*16*128*8;
  #pragma unroll
  for(int ks=0; ks<4; ks++){
    f16x8 af[4], bf[4];
    #pragma unroll
    for(int mt=0; mt<4; mt++)
      af[mt] = *(const f16x8*)(xs + (wr*64 + mt*16 + mq)*136 + ks*32 + quad*8);
    #pragma unroll
    for(int nt=0; nt<4; nt++){
      int c  = wc*64 + nt*16 + mq;
      int fc = ks*4 + quad;
      bf[nt] = *(const f16x8*)(wh + (fc*128 + c)*8);
    }
    #pragma unroll
    for(int mt=0; mt<4; mt++)
      #pragma unroll
      for(int nt=0; nt<4; nt++)
        acc[mt][nt] = __builtin_amdgcn_mfma_f32_16x16x32_f16(af[mt], bf[nt], acc[mt][nt], 0,0,0);
  }
  __syncthreads();          // xs dead -> reuse as tanh tile
  f16* tt = xs;             // [128][136]
  f16* hpb = hpB + (long)(b*8+h)*128*128*8;
  #pragma unroll
  for(int mt=0; mt<4; mt++){
    #pragma unroll
    for(int nt=0; nt<4; nt++){
      int c = wc*64 + nt*16 + mq;
      f16x4 pk;
      #pragma unroll
      for(int rg=0; rg<4; rg++){
        float v = acc[mt][nt][rg];
        pk[rg] = (f16)v;
        int il = wr*64 + mt*16 + quad*4 + rg;    // 0..127
        float e2 = __expf(2.0f*v);
        float th = 1.0f - 2.0f*__builtin_amdgcn_rcpf(e2 + 1.0f);
        tt[il*136 + c] = (f16)th;
      }
      int il0 = wr*64 + mt*16 + quad*4;
      int inode = i0 + il0;
      *(f16x4*)(hpb + ((long)(inode>>3)*128 + c)*8 + (inode&7)) = pk;  // 8B packed store
    }
  }
  __syncthreads();
  {
    int r = t>>1, hf = t&1;
    float s_p = 0.f, d_p = 0.f;
    #pragma unroll
    for(int q=0;q<8;q++){
      f16x8 tv = *(const f16x8*)(tt + r*136 + hf*64 + q*8);
      #pragma unroll
      for(int j=0;j<8;j++){
        float tvf = (float)tv[j];
        int c = hf*64 + q*8 + j;
        s_p = fmaf(tvf, asl[c], s_p);
        d_p = fmaf(tvf, adl[c], d_p);
      }
    }
    s_p += __shfl_xor(s_p, 1);
    d_p += __shfl_xor(d_p, 1);
    if (hf == 0){
      sarr[(b*8+h)*1024 + i0 + r] = s_p;
      darr[(b*8+h)*1024 + i0 + r] = d_p;
    }
  }
}

// ---------------- attention (row-split, batched sparse P-fill, pipelined) ----------------
// grid: 1024 blocks: bid = it*64 + bh  (same-bh blocks -> XCD bh%8 == h, matching k_hp)
// Each block: 64 rows x all 1024 cols; part stored normalized*(1/8).
// P-fill: the old while(ctz) loop serialized one dependent ~120cy ds_read per set bit
// (~500-600cy/tile exposed).  Now: ctz-chain extracts up to 4 indices (pure VALU),
// the 4 LDS loads issue together (one ~120cy latency), exps computed batch-wise.
// Wave-level exp count unchanged (exec-masked lanes issue anyway) -> no R2-style
// TRANS-pressure regression.  Rare >4-bits-per-16-col-window falls back to the loop.
__global__ __launch_bounds__(256,4) void k_attn(
    const f16* __restrict__ hpB,      // [B*H][128][128][8]  (jc, c, e)
    const float* __restrict__ sarr, const float* __restrict__ darr,
    const unsigned* __restrict__ am,  // [B*1024][32]
    f16* __restrict__ part)           // [64][1024][128] f16, normalized * 0.125
{
  __shared__ float ddl[1024];         // log2e-scaled d, all columns
  __shared__ float wred[4];
  __shared__ float zl[64];
  __shared__ f16 Pl[2][64*72];        // P tiles, row stride 72 f16 (144B, 16B aligned)
  int t = threadIdx.x;
  int bid = blockIdx.x;
  int bh = bid & 63, it = bid >> 6;
  int i0 = it*64;
  int b = bh >> 3;

  int lane = t&63, wv = t>>6;
  int mq = lane&15, quad = lane>>4;
  const f16* hpb = hpB + (long)bh*128*128*8;

  // stage scaled d (all 1024) + global max of d
  {
    float4 v = *(const float4*)(darr + bh*1024 + t*4);
    float mx = fmaxf(fmaxf(v.x,v.y), fmaxf(v.z,v.w));
    #pragma unroll
    for(int o=1;o<64;o<<=1) mx = fmaxf(mx, __shfl_xor(mx, o));
    if (lane == 0) wred[wv] = mx;
    *(float4*)(ddl + t*4) = make_float4(v.x*L2E, v.y*L2E, v.z*L2E, v.w*L2E);
  }

  int prow = t>>2, pg = t&3;          // row 0..63, 16-col group 0..3
  float srowl = sarr[bh*1024 + i0 + prow] * L2E;
  const unsigned* amrow = am + ((long)(b*1024 + i0 + prow))*32;
  int wsel = pg >> 1, wsh = (pg&1)*16;

  // prefetch B fragments + mask words for tiles 0/1 (no LDS dependency yet)
  f16x8 bcur[4], bnx[4];
  #pragma unroll
  for(int kk=0;kk<2;kk++)
    #pragma unroll
    for(int nt=0;nt<2;nt++){
      int c  = wv*32 + nt*16 + mq;
      int jc = kk*4 + quad;
      bcur[kk*2+nt] = *(const f16x8*)(hpb + ((long)jc*128 + c)*8);
    }
  unsigned wcur = amrow[wsel];
  unsigned wnx  = amrow[2 + wsel];

  __syncthreads();
  float Dml = fmaxf(fmaxf(wred[0],wred[1]), fmaxf(wred[2],wred[3])) * L2E;
  float ml = srowl + Dml;
  float mrowl = fmaxf(ml, 0.2f*ml);   // log2-domain upper bound of masked scores

  f32x4 acc[4][2];
  #pragma unroll
  for(int a=0;a<4;a++){ acc[a][0] = (f32x4){0.f,0.f,0.f,0.f}; acc[a][1] = (f32x4){0.f,0.f,0.f,0.f}; }
  float zacc = 0.f;
  f16x8 zerov = (f16x8){0,0,0,0,0,0,0,0};

  // batched sparse P-fill, used for tile 0 and inside the main loop
#define PFILL(BUF, WORDSRC, DBASE)                                        \
  {                                                                       \
    f16* myp = Pl[BUF] + prow*72 + pg*16;                                 \
    *(f16x8*)myp = zerov; *(f16x8*)(myp+8) = zerov;                       \
    unsigned word = ((WORDSRC) >> wsh) & 0xffffu;                         \
    const float* dloc = ddl + (DBASE) + pg*16;                            \
    if (word){                                                            \
      int n = __popc(word);                                               \
      unsigned w = word;                                                  \
      int j0 = __builtin_ctz(w); w &= w-1u;                               \
      int j1 = w ? __builtin_ctz(w) : j0; w = w ? (w & (w-1u)) : 0u;      \
      int j2 = w ? __builtin_ctz(w) : j0; w = w ? (w & (w-1u)) : 0u;      \
      int j3 = w ? __builtin_ctz(w) : j0;                                 \
      unsigned wrest = w ? (w & (w-1u)) : 0u;                             \
      float v0 = dloc[j0], v1 = dloc[j1], v2 = dloc[j2], v3 = dloc[j3];   \
      float x0 = srowl+v0, x1 = srowl+v1, x2 = srowl+v2, x3 = srowl+v3;   \
      float e0 = __builtin_amdgcn_exp2f(fmaxf(x0,0.2f*x0) - mrowl);       \
      float e1 = __builtin_amdgcn_exp2f(fmaxf(x1,0.2f*x1) - mrowl);      \
      float e2 = __builtin_amdgcn_exp2f(fmaxf(x2,0.2f*x2) - mrowl);      \
      float e3 = __builtin_amdgcn_exp2f(fmaxf(x3,0.2f*x3) - mrowl);      \
      zacc += e0; myp[j0] = (f16)e0;                                      \
      if (n > 1){ zacc += e1; myp[j1] = (f16)e1; }                        \
      if (n > 2){ zacc += e2; myp[j2] = (f16)e2; }                        \
      if (n > 3){ zacc += e3; myp[j3] = (f16)e3; }                        \
      while (wrest){                                                      \
        int j = __builtin_ctz(wrest); wrest &= wrest-1u;                  \
        float xl = srowl + dloc[j];                                       \
        float e  = __builtin_amdgcn_exp2f(fmaxf(xl,0.2f*xl) - mrowl);     \
        zacc += e; myp[j] = (f16)e;                                       \
      }                                                                   \
    }                                                                     \
  }

  PFILL(0, wcur, 0)
  __syncthreads();

  for(int jt=0; jt<16; jt++){
    if (jt < 15){
      // prefetch B fragments for tile jt+1
      #pragma unroll
      for(int kk=0;kk<2;kk++)
        #pragma unroll
        for(int nt=0;nt<2;nt++){
          int c  = wv*32 + nt*16 + mq;
          int jc = (jt+1)*8 + kk*4 + quad;
          bnx[kk*2+nt] = *(const f16x8*)(hpb + ((long)jc*128 + c)*8);
        }
      unsigned wfut = (jt < 14) ? amrow[(jt+2)*2 + wsel] : 0u;
      // fill tile jt+1 into the other buffer (disjoint from MFMA reads of tile jt)
      PFILL((jt+1)&1, wnx, (jt+1)*64)
      wnx = wfut;
    }
    const f16* Pc = Pl[jt&1];
    #pragma unroll
    for(int kk=0;kk<2;kk++){
      #pragma unroll
      for(int mt=0;mt<4;mt++){
        f16x8 a = *(const f16x8*)(Pc + (mt*16+mq)*72 + kk*32 + quad*8);
        #pragma unroll
        for(int nt=0;nt<2;nt++)
          acc[mt][nt] = __builtin_amdgcn_mfma_f32_16x16x32_f16(a, bcur[kk*2+nt], acc[mt][nt], 0,0,0);
      }
    }
    __syncthreads();
    if (jt < 15){
      #pragma unroll
      for(int q=0;q<4;q++) bcur[q] = bnx[q];
    }
  }
#undef PFILL

  // full softmax denominator per row (4-lane group covers all 1024 cols)
  zacc += __shfl_xor(zacc, 1);
  zacc += __shfl_xor(zacc, 2);
  if (pg == 0) zl[prow] = zacc;
  __syncthreads();

  // normalize + head-prescale, transpose through LDS for coalesced f16x8 stores
  f16* Ps = (f16*)Pl;                  // [64][136] f16 (272B stride, 16B aligned)
  #pragma unroll
  for(int mt=0;mt<4;mt++){
    #pragma unroll
    for(int rg=0;rg<4;rg++){
      int il = mt*16 + quad*4 + rg;
      float zi = 0.125f * __builtin_amdgcn_rcpf(zl[il]);
      #pragma unroll
      for(int nt=0;nt<2;nt++){
        int c = wv*32 + nt*16 + mq;
        Ps[il*136 + c] = (f16)(acc[mt][nt][rg] * zi);
      }
    }
  }
  __syncthreads();
  {
    int r = t>>2, g = t&3;
    f16* dst = part + ((long)bh*1024 + i0 + r)*128 + g*32;
    const f16* srcp = Ps + r*136 + g*32;
    *(f16x8*)(dst)    = *(const f16x8*)(srcp);
    *(f16x8*)(dst+8)  = *(const f16x8*)(srcp+8);
    *(f16x8*)(dst+16) = *(const f16x8*)(srcp+16);
    *(f16x8*)(dst+24) = *(const f16x8*)(srcp+24);
  }
}

// ---------------- finalize: sum heads (already normalized+prescaled), bias(+relu), partial node-max ----------------
// 512 blocks x 256: block covers one b, 16 nodes, all 128 channels
__global__ void k_fin(const f16* __restrict__ part, const float* __restrict__ bias,
                      f16* __restrict__ x16, float* __restrict__ pmax, int do_relu){
  __shared__ float pm[16][128];
  int t = threadIdx.x;
  int idx = blockIdx.x*256 + t;   // b(3)|n(10)|c8(4)
  int c8 = idx & 15, n = (idx>>4)&1023, b = idx>>14;
  float s[8];
  #pragma unroll
  for(int j=0;j<8;j++) s[j] = 0.f;
  #pragma unroll
  for(int h=0;h<8;h++){
    int bh = b*8 + h;
    f16x8 p0 = *(const f16x8*)(part + ((long)bh*1024 + n)*128 + c8*8);
    #pragma unroll
    for(int j=0;j<8;j++) s[j] += (float)p0[j];
  }
  f16x8 h8;
  float ov[8];
  #pragma unroll
  for(int j=0;j<8;j++){
    float v = s[j] + bias[c8*8 + j];
    if (do_relu) v = fmaxf(v, 0.f);
    ov[j] = v;
    h8[j] = (f16)v;
  }
  if (x16) *(f16x8*)(x16 + ((long)(b*1024+n))*128 + c8*8) = h8;
  #pragma unroll
  for(int j=0;j<8;j++) pm[n&15][c8*8+j] = ov[j];
  __syncthreads();
  if (t < 128){
    float m = pm[0][t];
    #pragma unroll
    for(int r=1;r<16;r++) m = fmaxf(m, pm[r][t]);
    pmax[blockIdx.x*128 + t] = m;   // [b*64+chunk][128]
  }
}

// ---------------- final: max over chunks + predictor ----------------
// 8 blocks x 256.  Coalesced chunk-max: lanes read consecutive channels (256B/wave)
// instead of the old stride-512B scalar walk; two half-partials combined in LDS.
__global__ void k_pool2(const float* __restrict__ pmax, const float* __restrict__ pw,
                        const float* __restrict__ pb, float* __restrict__ out){
  __shared__ float ph[2][384];
  __shared__ float pl[384];
  int b = blockIdx.x, t = threadIdx.x;
  int c = t & 127, half = t >> 7;
  #pragma unroll
  for(int l=0;l<3;l++){
    const float* p = pmax + l*65536 + b*8192 + half*32*128 + c;
    float m = -3.4e38f;
    #pragma unroll 8
    for(int kk=0;kk<32;kk++) m = fmaxf(m, p[kk*128]);
    ph[half][l*128 + c] = m;
  }
  __syncthreads();
  for(int f = t; f < 384; f += 256) pl[f] = fmaxf(ph[0][f], ph[1][f]);
  __syncthreads();
  if (t < 64){
    float a0 = 0.f, a1 = 0.f;
    #pragma unroll
    for(int k=0;k<6;k++){
      int f = t + 64*k;
      float v = pl[f];
      a0 = fmaf(v, pw[f*2],   a0);
      a1 = fmaf(v, pw[f*2+1], a1);
    }
    #pragma unroll
    for(int o=1;o<64;o<<=1){ a0 += __shfl_xor(a0,o); a1 += __shfl_xor(a1,o); }
    if (t == 0){ out[b*2] = a0 + pb[0]; out[b*2+1] = a1 + pb[1]; }
  }
}

// ---------------- launcher ----------------
extern "C" void kernel_launch(void* const* d_in, const int* in_sizes, int n_in,
                              void* d_out, int out_size, void* d_ws, size_t ws_size,
                              hipStream_t stream) {
  const float* x   = (const float*)d_in[0];
  const float* adj = (const float*)d_in[1];
  const float* w1  = (const float*)d_in[2];
  const float* as1 = (const float*)d_in[3];
  const float* ad1 = (const float*)d_in[4];
  const float* b1  = (const float*)d_in[5];
  const float* w2  = (const float*)d_in[6];
  const float* as2 = (const float*)d_in[7];
  const float* ad2 = (const float*)d_in[8];
  const float* b2  = (const float*)d_in[9];
  const float* w3  = (const float*)d_in[10];
  const float* as3 = (const float*)d_in[11];
  const float* ad3 = (const float*)d_in[12];
  const float* b3  = (const float*)d_in[13];
  const float* pw  = (const float*)d_in[14];
  const float* pb  = (const float*)d_in[15];

  char* ws = (char*)d_ws;
  f16*      x16a = (f16*)ws;                 ws += (size_t)1048576*2;
  f16*      x16b = (f16*)ws;                 ws += (size_t)1048576*2;
  f16*      wB   = (f16*)ws;                 ws += (size_t)393216*2;
  unsigned* am   = (unsigned*)ws;            ws += (size_t)8*1024*32*4;
  f16*      hpB  = (f16*)ws;                 ws += (size_t)8*8*1024*128*2;
  float*    sarr = (float*)ws;               ws += (size_t)65536*4;
  float*    darr = (float*)ws;               ws += (size_t)65536*4;
  f16*      part = (f16*)ws;                 ws += (size_t)64*1024*128*2;
  float*    pmax = (float*)ws;               ws += (size_t)3*512*128*4;

  k_pre<<<2752, 256, 0, stream>>>(x, x16a, w1, w2, w3, wB, adj, am);

  // layer 1
  k_hp  <<<512, 256, 0, stream>>>(x16a, wB,            as1, ad1, hpB, sarr, darr);
  k_attn<<<1024,256, 0, stream>>>(hpB, sarr, darr, am, part);
  k_fin <<<512, 256, 0, stream>>>(part, b1, x16b, pmax,           1);
  // layer 2
  k_hp  <<<512, 256, 0, stream>>>(x16b, wB + 131072,   as2, ad2, hpB, sarr, darr);
  k_attn<<<1024,256, 0, stream>>>(hpB, sarr, darr, am, part);
  k_fin <<<512, 256, 0, stream>>>(part, b2, x16a, pmax + 65536,   1);
  // layer 3
  k_hp  <<<512, 256, 0, stream>>>(x16a, wB + 262144,   as3, ad3, hpB, sarr, darr);
  k_attn<<<1024,256, 0, stream>>>(hpB, sarr, darr, am, part);
  k_fin <<<512, 256, 0, stream>>>(part, b3, nullptr, pmax + 131072, 0);

  k_pool2<<<8, 256, 0, stream>>>(pmax, pw, pb, (float*)d_out);
}

// Round 5
// 248.868 us; speedup vs baseline: 1.1154x; 1.0240x over previous
//
#include <hip/hip_runtime.h>
#include <hip/hip_fp16.h>

#define BB 8
#define NN 1024
#define FF 128
#define HH 8

typedef _Float16 f16;
typedef f16  f16x8 __attribute__((ext_vector_type(8)));
typedef f16  f16x4 __attribute__((ext_vector_type(4)));
typedef float f32x4 __attribute__((ext_vector_type(4)));

#define L2E 1.44269504f

// ---------------- fused preprocessing: conv_x | conv_w | adj bitmask ----------------
// blocks 0..511: x->f16; 512..703: w->wB; 704..2751: adj->bitmask
__global__ void k_pre(const float* __restrict__ x, f16* __restrict__ x16a,
                      const float* __restrict__ w1, const float* __restrict__ w2,
                      const float* __restrict__ w3, f16* __restrict__ wB,
                      const float* __restrict__ adj, unsigned* __restrict__ am){
  int bid = blockIdx.x, t = threadIdx.x;
  if (bid < 512){
    int i = (bid*256 + t)*8;
    float4 a = *(const float4*)(x+i), b = *(const float4*)(x+i+4);
    f16x8 v;
    v[0]=(f16)a.x; v[1]=(f16)a.y; v[2]=(f16)a.z; v[3]=(f16)a.w;
    v[4]=(f16)b.x; v[5]=(f16)b.y; v[6]=(f16)b.z; v[7]=(f16)b.w;
    *(f16x8*)(x16a+i) = v;
  } else if (bid < 704){
    int e = (bid-512)*256 + t;                 // 49152 total
    int fc = e & 15, c = (e>>4)&127, h = (e>>11)&7, l = e>>14;
    const float* w = (l==0) ? w1 : ((l==1) ? w2 : w3);
    f16x8 v;
    #pragma unroll
    for(int j=0;j<8;j++) v[j] = (f16)w[(h*128 + fc*8 + j)*128 + c];
    *(f16x8*)(wB + (((l*8+h)*16 + fc)*128 + c)*8) = v;
  } else {
    int wv = t >> 6, lane = t & 63;
    int r = (bid-704)*4 + wv;                  // 0..8191
    const float* row = adj + (long)r*1024;
    for(int g=0; g<16; g++){
      float v = row[g*64 + lane];
      unsigned long long mb = __ballot(v > 0.0f);
      if (lane == 0){
        am[r*32 + 2*g]   = (unsigned)mb;
        am[r*32 + 2*g+1] = (unsigned)(mb >> 32);
      }
    }
  }
}

// ---------------- hp GEMM: hp = x @ w  (+tanh -> s,d) ----------------
// grid: 512 blocks, 256 threads.  bid decode: h = bid&7 so XCD(bid%8)==h  (neutral in
// R3 A/B, kept: mechanism sound, no measured harm).
// hpB layout: [b][h][jc=node/8][c][8]
__global__ __launch_bounds__(256,2) void k_hp(
    const f16* __restrict__ xin,      // [B][N][128] f16
    const f16* __restrict__ wBl,      // [H][16][128][8]
    const float* __restrict__ asrc, const float* __restrict__ adst,  // [H][128]
    f16* __restrict__ hpB,            // [B][H][128][128][8]
    float* __restrict__ sarr, float* __restrict__ darr)              // [B][H][1024]
{
  __shared__ f16 xs[128*136];     // x tile, later reused as tanh tile
  __shared__ float asl[128], adl[128];
  int t = threadIdx.x;
  int bid = blockIdx.x;
  int h = bid & 7, it = (bid>>3)&7, b = bid>>6;   // XCD affinity: bid%8 == h
  int i0 = it*128;
  {
    const f16* src = xin + (long)(b*1024 + i0)*128;
    int fc = t & 15, r0 = t >> 4;
    #pragma unroll
    for(int p=0;p<8;p++){
      int r = r0 + p*16;
      f16x8 v = *(const f16x8*)(src + r*128 + fc*8);
      *(f16x8*)(xs + r*136 + fc*8) = v;
    }
  }
  if (t < 128){ asl[t] = asrc[h*128+t]; adl[t] = adst[h*128+t]; }
  __syncthreads();

  int lane = t & 63, wv = t>>6, wr = wv>>1, wc = wv&1;
  int mq = lane & 15, quad = lane >> 4;
  f32x4 acc[4][4];
  #pragma unroll
  for(int a=0;a<4;a++)
    #pragma unroll
    for(int c=0;c<4;c++) acc[a][c] = (f32x4){0.f,0.f,0.f,0.f};

  const f16* wh = wBl + h*16*128*8;
  #pragma unroll
  for(int ks=0; ks<4; ks++){
    f16x8 af[4], bf[4];
    #pragma unroll
    for(int mt=0; mt<4; mt++)
      af[mt] = *(const f16x8*)(xs + (wr*64 + mt*16 + mq)*136 + ks*32 + quad*8);
    #pragma unroll
    for(int nt=0; nt<4; nt++){
      int c  = wc*64 + nt*16 + mq;
      int fc = ks*4 + quad;
      bf[nt] = *(const f16x8*)(wh + (fc*128 + c)*8);
    }
    #pragma unroll
    for(int mt=0; mt<4; mt++)
      #pragma unroll
      for(int nt=0; nt<4; nt++)
        acc[mt][nt] = __builtin_amdgcn_mfma_f32_16x16x32_f16(af[mt], bf[nt], acc[mt][nt], 0,0,0);
  }
  __syncthreads();          // xs dead -> reuse as tanh tile
  f16* tt = xs;             // [128][136]
  f16* hpb = hpB + (long)(b*8+h)*128*128*8;
  #pragma unroll
  for(int mt=0; mt<4; mt++){
    #pragma unroll
    for(int nt=0; nt<4; nt++){
      int c = wc*64 + nt*16 + mq;
      f16x4 pk;
      #pragma unroll
      for(int rg=0; rg<4; rg++){
        float v = acc[mt][nt][rg];
        pk[rg] = (f16)v;
        int il = wr*64 + mt*16 + quad*4 + rg;    // 0..127
        float e2 = __expf(2.0f*v);
        float th = 1.0f - 2.0f*__builtin_amdgcn_rcpf(e2 + 1.0f);
        tt[il*136 + c] = (f16)th;
      }
      int il0 = wr*64 + mt*16 + quad*4;
      int inode = i0 + il0;
      *(f16x4*)(hpb + ((long)(inode>>3)*128 + c)*8 + (inode&7)) = pk;  // 8B packed store
    }
  }
  __syncthreads();
  {
    int r = t>>1, hf = t&1;
    float s_p = 0.f, d_p = 0.f;
    #pragma unroll
    for(int q=0;q<8;q++){
      f16x8 tv = *(const f16x8*)(tt + r*136 + hf*64 + q*8);
      #pragma unroll
      for(int j=0;j<8;j++){
        float tvf = (float)tv[j];
        int c = hf*64 + q*8 + j;
        s_p = fmaf(tvf, asl[c], s_p);
        d_p = fmaf(tvf, adl[c], d_p);
      }
    }
    s_p += __shfl_xor(s_p, 1);
    d_p += __shfl_xor(d_p, 1);
    if (hf == 0){
      sarr[(b*8+h)*1024 + i0 + r] = s_p;
      darr[(b*8+h)*1024 + i0 + r] = d_p;
    }
  }
}

// ---------------- attention (row-split, batched sparse P-fill, depth-2 pipelined) ----------------
// grid: 1024 blocks: bid = it*64 + bh  (same-bh blocks -> XCD bh%8 == h, matching k_hp)
// Each block: 64 rows x all 1024 cols; part stored normalized*(1/8).
// R5: B-fragment prefetch deepened to 2 tiles (triple buffer bf[3][4]); jt loop fully
// unrolled so the mod-3 rotation is static register naming (no v_mov chains, no
// runtime-indexed array -> scratch).  Gives L2 loads ~2 phases (~600cy) of cover
// instead of ~1 (~300cy).  PFILL stays 1-deep (LDS double buffer).
__global__ __launch_bounds__(256,4) void k_attn(
    const f16* __restrict__ hpB,      // [B*H][128][128][8]  (jc, c, e)
    const float* __restrict__ sarr, const float* __restrict__ darr,
    const unsigned* __restrict__ am,  // [B*1024][32]
    f16* __restrict__ part)           // [64][1024][128] f16, normalized * 0.125
{
  __shared__ float ddl[1024];         // log2e-scaled d, all columns
  __shared__ float wred[4];
  __shared__ float zl[64];
  __shared__ f16 Pl[2][64*72];        // P tiles, row stride 72 f16 (144B, 16B aligned)
  int t = threadIdx.x;
  int bid = blockIdx.x;
  int bh = bid & 63, it = bid >> 6;
  int i0 = it*64;
  int b = bh >> 3;

  int lane = t&63, wv = t>>6;
  int mq = lane&15, quad = lane>>4;
  const f16* hpb = hpB + (long)bh*128*128*8;

  // stage scaled d (all 1024) + global max of d
  {
    float4 v = *(const float4*)(darr + bh*1024 + t*4);
    float mx = fmaxf(fmaxf(v.x,v.y), fmaxf(v.z,v.w));
    #pragma unroll
    for(int o=1;o<64;o<<=1) mx = fmaxf(mx, __shfl_xor(mx, o));
    if (lane == 0) wred[wv] = mx;
    *(float4*)(ddl + t*4) = make_float4(v.x*L2E, v.y*L2E, v.z*L2E, v.w*L2E);
  }

  int prow = t>>2, pg = t&3;          // row 0..63, 16-col group 0..3
  float srowl = sarr[bh*1024 + i0 + prow] * L2E;
  const unsigned* amrow = am + ((long)(b*1024 + i0 + prow))*32;
  int wsel = pg >> 1, wsh = (pg&1)*16;

  // prefetch B fragments for tiles 0 and 1 + mask words for tiles 0/1 (no LDS dep yet)
  f16x8 bf[3][4];
  #pragma unroll
  for(int kk=0;kk<2;kk++)
    #pragma unroll
    for(int nt=0;nt<2;nt++){
      int c  = wv*32 + nt*16 + mq;
      bf[0][kk*2+nt] = *(const f16x8*)(hpb + ((long)(kk*4 + quad)*128 + c)*8);
      bf[1][kk*2+nt] = *(const f16x8*)(hpb + ((long)(8 + kk*4 + quad)*128 + c)*8);
    }
  unsigned wcur = amrow[wsel];
  unsigned wnx  = amrow[2 + wsel];

  __syncthreads();
  float Dml = fmaxf(fmaxf(wred[0],wred[1]), fmaxf(wred[2],wred[3])) * L2E;
  float ml = srowl + Dml;
  float mrowl = fmaxf(ml, 0.2f*ml);   // log2-domain upper bound of masked scores

  f32x4 acc[4][2];
  #pragma unroll
  for(int a=0;a<4;a++){ acc[a][0] = (f32x4){0.f,0.f,0.f,0.f}; acc[a][1] = (f32x4){0.f,0.f,0.f,0.f}; }
  float zacc = 0.f;
  f16x8 zerov = (f16x8){0,0,0,0,0,0,0,0};

  // batched sparse P-fill (R4): ctz-chain extracts up to 4 indices, the 4 LDS loads
  // issue together (one ~120cy latency), rare >4-bit fallback loop
#define PFILL(BUF, WORDSRC, DBASE)                                        \
  {                                                                       \
    f16* myp = Pl[BUF] + prow*72 + pg*16;                                 \
    *(f16x8*)myp = zerov; *(f16x8*)(myp+8) = zerov;                       \
    unsigned word = ((WORDSRC) >> wsh) & 0xffffu;                         \
    const float* dloc = ddl + (DBASE) + pg*16;                            \
    if (word){                                                            \
      int n = __popc(word);                                               \
      unsigned w = word;                                                  \
      int j0 = __builtin_ctz(w); w &= w-1u;                               \
      int j1 = w ? __builtin_ctz(w) : j0; w = w ? (w & (w-1u)) : 0u;      \
      int j2 = w ? __builtin_ctz(w) : j0; w = w ? (w & (w-1u)) : 0u;      \
      int j3 = w ? __builtin_ctz(w) : j0;                                 \
      unsigned wrest = w ? (w & (w-1u)) : 0u;                             \
      float v0 = dloc[j0], v1 = dloc[j1], v2 = dloc[j2], v3 = dloc[j3];   \
      float x0 = srowl+v0, x1 = srowl+v1, x2 = srowl+v2, x3 = srowl+v3;   \
      float e0 = __builtin_amdgcn_exp2f(fmaxf(x0,0.2f*x0) - mrowl);       \
      float e1 = __builtin_amdgcn_exp2f(fmaxf(x1,0.2f*x1) - mrowl);      \
      float e2 = __builtin_amdgcn_exp2f(fmaxf(x2,0.2f*x2) - mrowl);      \
      float e3 = __builtin_amdgcn_exp2f(fmaxf(x3,0.2f*x3) - mrowl);      \
      zacc += e0; myp[j0] = (f16)e0;                                      \
      if (n > 1){ zacc += e1; myp[j1] = (f16)e1; }                        \
      if (n > 2){ zacc += e2; myp[j2] = (f16)e2; }                        \
      if (n > 3){ zacc += e3; myp[j3] = (f16)e3; }                        \
      while (wrest){                                                      \
        int j = __builtin_ctz(wrest); wrest &= wrest-1u;                  \
        float xl = srowl + dloc[j];                                       \
        float e  = __builtin_amdgcn_exp2f(fmaxf(xl,0.2f*xl) - mrowl);     \
        zacc += e; myp[j] = (f16)e;                                       \
      }                                                                   \
    }                                                                     \
  }

  PFILL(0, wcur, 0)
  __syncthreads();

  #pragma unroll
  for(int jt=0; jt<16; jt++){
    if (jt < 14){
      // issue B fragments for tile jt+2 (consumed two phases later)
      #pragma unroll
      for(int kk=0;kk<2;kk++)
        #pragma unroll
        for(int nt=0;nt<2;nt++){
          int c  = wv*32 + nt*16 + mq;
          int jc = (jt+2)*8 + kk*4 + quad;
          bf[(jt+2)%3][kk*2+nt] = *(const f16x8*)(hpb + ((long)jc*128 + c)*8);
        }
    }
    if (jt < 15){
      unsigned wfut = (jt < 14) ? amrow[(jt+2)*2 + wsel] : 0u;
      // fill tile jt+1 into the other buffer (disjoint from MFMA reads of tile jt)
      PFILL((jt+1)&1, wnx, (jt+1)*64)
      wnx = wfut;
    }
    const f16* Pc = Pl[jt&1];
    #pragma unroll
    for(int kk=0;kk<2;kk++){
      #pragma unroll
      for(int mt=0;mt<4;mt++){
        f16x8 a = *(const f16x8*)(Pc + (mt*16+mq)*72 + kk*32 + quad*8);
        #pragma unroll
        for(int nt=0;nt<2;nt++)
          acc[mt][nt] = __builtin_amdgcn_mfma_f32_16x16x32_f16(a, bf[jt%3][kk*2+nt], acc[mt][nt], 0,0,0);
      }
    }
    __syncthreads();
  }
#undef PFILL

  // full softmax denominator per row (4-lane group covers all 1024 cols)
  zacc += __shfl_xor(zacc, 1);
  zacc += __shfl_xor(zacc, 2);
  if (pg == 0) zl[prow] = zacc;
  __syncthreads();

  // normalize + head-prescale, transpose through LDS for coalesced f16x8 stores
  f16* Ps = (f16*)Pl;                  // [64][136] f16 (272B stride, 16B aligned)
  #pragma unroll
  for(int mt=0;mt<4;mt++){
    #pragma unroll
    for(int rg=0;rg<4;rg++){
      int il = mt*16 + quad*4 + rg;
      float zi = 0.125f * __builtin_amdgcn_rcpf(zl[il]);
      #pragma unroll
      for(int nt=0;nt<2;nt++){
        int c = wv*32 + nt*16 + mq;
        Ps[il*136 + c] = (f16)(acc[mt][nt][rg] * zi);
      }
    }
  }
  __syncthreads();
  {
    int r = t>>2, g = t&3;
    f16* dst = part + ((long)bh*1024 + i0 + r)*128 + g*32;
    const f16* srcp = Ps + r*136 + g*32;
    *(f16x8*)(dst)    = *(const f16x8*)(srcp);
    *(f16x8*)(dst+8)  = *(const f16x8*)(srcp+8);
    *(f16x8*)(dst+16) = *(const f16x8*)(srcp+16);
    *(f16x8*)(dst+24) = *(const f16x8*)(srcp+24);
  }
}

// ---------------- finalize: sum heads (already normalized+prescaled), bias(+relu), partial node-max ----------------
// 512 blocks x 256: block covers one b, 16 nodes, all 128 channels
__global__ void k_fin(const f16* __restrict__ part, const float* __restrict__ bias,
                      f16* __restrict__ x16, float* __restrict__ pmax, int do_relu){
  __shared__ float pm[16][128];
  int t = threadIdx.x;
  int idx = blockIdx.x*256 + t;   // b(3)|n(10)|c8(4)
  int c8 = idx & 15, n = (idx>>4)&1023, b = idx>>14;
  float s[8];
  #pragma unroll
  for(int j=0;j<8;j++) s[j] = 0.f;
  #pragma unroll
  for(int h=0;h<8;h++){
    int bh = b*8 + h;
    f16x8 p0 = *(const f16x8*)(part + ((long)bh*1024 + n)*128 + c8*8);
    #pragma unroll
    for(int j=0;j<8;j++) s[j] += (float)p0[j];
  }
  f16x8 h8;
  float ov[8];
  #pragma unroll
  for(int j=0;j<8;j++){
    float v = s[j] + bias[c8*8 + j];
    if (do_relu) v = fmaxf(v, 0.f);
    ov[j] = v;
    h8[j] = (f16)v;
  }
  if (x16) *(f16x8*)(x16 + ((long)(b*1024+n))*128 + c8*8) = h8;
  #pragma unroll
  for(int j=0;j<8;j++) pm[n&15][c8*8+j] = ov[j];
  __syncthreads();
  if (t < 128){
    float m = pm[0][t];
    #pragma unroll
    for(int r=1;r<16;r++) m = fmaxf(m, pm[r][t]);
    pmax[blockIdx.x*128 + t] = m;   // [b*64+chunk][128]
  }
}

// ---------------- final: max over chunks + predictor ----------------
// 8 blocks x 256.  Coalesced chunk-max: lanes read consecutive channels (256B/wave)
// instead of a stride-512B scalar walk; two half-partials combined in LDS.
__global__ void k_pool2(const float* __restrict__ pmax, const float* __restrict__ pw,
                        const float* __restrict__ pb, float* __restrict__ out){
  __shared__ float ph[2][384];
  __shared__ float pl[384];
  int b = blockIdx.x, t = threadIdx.x;
  int c = t & 127, half = t >> 7;
  #pragma unroll
  for(int l=0;l<3;l++){
    const float* p = pmax + l*65536 + b*8192 + half*32*128 + c;
    float m = -3.4e38f;
    #pragma unroll 8
    for(int kk=0;kk<32;kk++) m = fmaxf(m, p[kk*128]);
    ph[half][l*128 + c] = m;
  }
  __syncthreads();
  for(int f = t; f < 384; f += 256) pl[f] = fmaxf(ph[0][f], ph[1][f]);
  __syncthreads();
  if (t < 64){
    float a0 = 0.f, a1 = 0.f;
    #pragma unroll
    for(int k=0;k<6;k++){
      int f = t + 64*k;
      float v = pl[f];
      a0 = fmaf(v, pw[f*2],   a0);
      a1 = fmaf(v, pw[f*2+1], a1);
    }
    #pragma unroll
    for(int o=1;o<64;o<<=1){ a0 += __shfl_xor(a0,o); a1 += __shfl_xor(a1,o); }
    if (t == 0){ out[b*2] = a0 + pb[0]; out[b*2+1] = a1 + pb[1]; }
  }
}

// ---------------- launcher ----------------
extern "C" void kernel_launch(void* const* d_in, const int* in_sizes, int n_in,
                              void* d_out, int out_size, void* d_ws, size_t ws_size,
                              hipStream_t stream) {
  const float* x   = (const float*)d_in[0];
  const float* adj = (const float*)d_in[1];
  const float* w1  = (const float*)d_in[2];
  const float* as1 = (const float*)d_in[3];
  const float* ad1 = (const float*)d_in[4];
  const float* b1  = (const float*)d_in[5];
  const float* w2  = (const float*)d_in[6];
  const float* as2 = (const float*)d_in[7];
  const float* ad2 = (const float*)d_in[8];
  const float* b2  = (const float*)d_in[9];
  const float* w3  = (const float*)d_in[10];
  const float* as3 = (const float*)d_in[11];
  const float* ad3 = (const float*)d_in[12];
  const float* b3  = (const float*)d_in[13];
  const float* pw  = (const float*)d_in[14];
  const float* pb  = (const float*)d_in[15];

  char* ws = (char*)d_ws;
  f16*      x16a = (f16*)ws;                 ws += (size_t)1048576*2;
  f16*      x16b = (f16*)ws;                 ws += (size_t)1048576*2;
  f16*      wB   = (f16*)ws;                 ws += (size_t)393216*2;
  unsigned* am   = (unsigned*)ws;            ws += (size_t)8*1024*32*4;
  f16*      hpB  = (f16*)ws;                 ws += (size_t)8*8*1024*128*2;
  float*    sarr = (float*)ws;               ws += (size_t)65536*4;
  float*    darr = (float*)ws;               ws += (size_t)65536*4;
  f16*      part = (f16*)ws;                 ws += (size_t)64*1024*128*2;
  float*    pmax = (float*)ws;               ws += (size_t)3*512*128*4;

  k_pre<<<2752, 256, 0, stream>>>(x, x16a, w1, w2, w3, wB, adj, am);

  // layer 1
  k_hp  <<<512, 256, 0, stream>>>(x16a, wB,            as1, ad1, hpB, sarr, darr);
  k_attn<<<1024,256, 0, stream>>>(hpB, sarr, darr, am, part);
  k_fin <<<512, 256, 0, stream>>>(part, b1, x16b, pmax,           1);
  // layer 2
  k_hp  <<<512, 256, 0, stream>>>(x16b, wB + 131072,   as2, ad2, hpB, sarr, darr);
  k_attn<<<1024,256, 0, stream>>>(hpB, sarr, darr, am, part);
  k_fin <<<512, 256, 0, stream>>>(part, b2, x16a, pmax + 65536,   1);
  // layer 3
  k_hp  <<<512, 256, 0, stream>>>(x16a, wB + 262144,   as3, ad3, hpB, sarr, darr);
  k_attn<<<1024,256, 0, stream>>>(hpB, sarr, darr, am, part);
  k_fin <<<512, 256, 0, stream>>>(part, b3, nullptr, pmax + 131072, 0);

  k_pool2<<<8, 256, 0, stream>>>(pmax, pw, pb, (float*)d_out);
}